// Round 2
// baseline (707.483 us; speedup 1.0000x reference)
//
#include <hip/hip_runtime.h>

#define D 64
#define IN 128
#define NEG_SLOPE 0.01f

// ---------------- Kernel 1: z = h @ fc_w^T, fused a_src/a_dst dots -----------
__global__ __launch_bounds__(256) void k_project(
    const float* __restrict__ h, const float* __restrict__ fc_w,
    const float* __restrict__ attn_w,
    float* __restrict__ z, float* __restrict__ a_src, float* __restrict__ a_dst,
    int n_nodes)
{
    __shared__ float w_lds[D][IN + 1];
    __shared__ float h_lds[4][IN];

    const int tid = threadIdx.x;
    for (int i = tid; i < D * IN; i += 256)
        w_lds[i / IN][i % IN] = fc_w[i];

    const int wave = tid >> 6;
    const int lane = tid & 63;
    const int node = blockIdx.x * 4 + wave;
    if (node < n_nodes) {
        h_lds[wave][lane]      = h[(size_t)node * IN + lane];
        h_lds[wave][lane + 64] = h[(size_t)node * IN + lane + 64];
    }
    __syncthreads();
    if (node >= n_nodes) return;

    float acc = 0.f;
    #pragma unroll
    for (int k = 0; k < IN; ++k)
        acc = fmaf(h_lds[wave][k], w_lds[lane][k], acc);

    z[(size_t)node * D + lane] = acc;

    float as = acc * attn_w[lane];
    float ad = acc * attn_w[D + lane];
    #pragma unroll
    for (int off = 32; off > 0; off >>= 1) {
        as += __shfl_xor(as, off, 64);
        ad += __shfl_xor(ad, off, 64);
    }
    if (lane == 0) { a_src[node] = as; a_dst[node] = ad; }
}

// ---------------- Kernel 2: degree histogram over dst ------------------------
__global__ __launch_bounds__(256) void k_hist(
    const int* __restrict__ dst, int* __restrict__ deg, int n_edges)
{
    int i = blockIdx.x * 256 + threadIdx.x;
    if (i >= n_edges) return;
    atomicAdd(&deg[dst[i]], 1);
}

// ---------------- Kernel 3: single-block exclusive scan ----------------------
// 1024 threads; thread t owns strip [t*per, (t+1)*per). Serial strip sums,
// Hillis-Steele scan of the 1024 strip totals, then serial prefix write.
__global__ __launch_bounds__(1024) void k_scan(
    const int* __restrict__ deg, int* __restrict__ off, int* __restrict__ cursor,
    int n, int per)
{
    __shared__ int lds[1024];
    const int t = threadIdx.x;
    const int t0 = t * per;

    int sum = 0;
    for (int j = 0; j < per; ++j) {
        int i = t0 + j;
        if (i < n) sum += deg[i];
    }
    lds[t] = sum;
    __syncthreads();
    for (int s = 1; s < 1024; s <<= 1) {
        int v = (t >= s) ? lds[t - s] : 0;
        __syncthreads();
        lds[t] += v;
        __syncthreads();
    }
    int run = lds[t] - sum;   // exclusive prefix of this strip
    for (int j = 0; j < per; ++j) {
        int i = t0 + j;
        if (i < n) {
            off[i] = run;
            cursor[i] = run;
            run += deg[i];
        }
    }
    if (t == 1023) off[n] = run;   // total = n_edges
}

// ---------------- Kernel 4: fill buckets (CSR by dst) ------------------------
// bucket[pos] = {e_logit, src_as_float_bits}
__global__ __launch_bounds__(256) void k_fill(
    const int* __restrict__ src, const int* __restrict__ dst,
    const float* __restrict__ a_src, const float* __restrict__ a_dst,
    int* __restrict__ cursor, float2* __restrict__ bucket, int n_edges)
{
    int i = blockIdx.x * 256 + threadIdx.x;
    if (i >= n_edges) return;
    int s = src[i], t = dst[i];
    float e = a_src[s] + a_dst[t];
    e = (e >= 0.f) ? e : NEG_SLOPE * e;
    int pos = atomicAdd(&cursor[t], 1);
    bucket[pos] = make_float2(e, __int_as_float(s));
}

// ---------------- Kernel 5: per-node softmax + weighted gather ---------------
// one wave per node, lane = output dim; zero atomics, one coalesced store
__global__ __launch_bounds__(256) void k_node(
    const int* __restrict__ off, const float2* __restrict__ bucket,
    const float* __restrict__ z, float* __restrict__ out, int n_nodes)
{
    int node = blockIdx.x * 4 + (threadIdx.x >> 6);
    if (node >= n_nodes) return;
    int lane = threadIdx.x & 63;
    int beg = off[node], end = off[node + 1];

    float m = -INFINITY;
    for (int j = beg; j < end; ++j)
        m = fmaxf(m, bucket[j].x);

    float den = 0.f, acc = 0.f;
    for (int j = beg; j < end; ++j) {
        float2 b = bucket[j];
        float w = __expf(b.x - m);
        den += w;
        int s = __float_as_int(b.y);
        acc = fmaf(w, z[(size_t)s * D + lane], acc);
    }
    out[(size_t)node * D + lane] = (end > beg) ? acc / den : 0.f;
}

extern "C" void kernel_launch(void* const* d_in, const int* in_sizes, int n_in,
                              void* d_out, int out_size, void* d_ws, size_t ws_size,
                              hipStream_t stream) {
    const float* h      = (const float*)d_in[0];
    const int*   src    = (const int*)d_in[1];
    const int*   dst    = (const int*)d_in[2];
    const float* fc_w   = (const float*)d_in[3];
    const float* attn_w = (const float*)d_in[4];

    const int n_nodes = in_sizes[0] / IN;
    const int n_edges = in_sizes[1];
    float* out = (float*)d_out;

    // workspace layout
    char* p = (char*)d_ws;
    float*  z      = (float*)p;  p += (size_t)n_nodes * D * sizeof(float);
    float*  a_src  = (float*)p;  p += (size_t)n_nodes * sizeof(float);
    float*  a_dst  = (float*)p;  p += (size_t)n_nodes * sizeof(float);
    int*    deg    = (int*)p;    p += (size_t)n_nodes * sizeof(int);
    int*    off    = (int*)p;    p += ((size_t)n_nodes + 1) * sizeof(int);
    int*    cursor = (int*)p;    p += (size_t)n_nodes * sizeof(int);
    float2* bucket = (float2*)p; p += (size_t)n_edges * sizeof(float2);

    hipMemsetAsync(deg, 0, (size_t)n_nodes * sizeof(int), stream);

    k_project<<<dim3((n_nodes + 3) / 4), dim3(256), 0, stream>>>(
        h, fc_w, attn_w, z, a_src, a_dst, n_nodes);
    k_hist<<<dim3((n_edges + 255) / 256), dim3(256), 0, stream>>>(
        dst, deg, n_edges);
    int per = (n_nodes + 1023) / 1024;
    k_scan<<<dim3(1), dim3(1024), 0, stream>>>(deg, off, cursor, n_nodes, per);
    k_fill<<<dim3((n_edges + 255) / 256), dim3(256), 0, stream>>>(
        src, dst, a_src, a_dst, cursor, bucket, n_edges);
    k_node<<<dim3((n_nodes + 3) / 4), dim3(256), 0, stream>>>(
        off, bucket, z, out, n_nodes);
}

// Round 3
// 451.470 us; speedup vs baseline: 1.5671x; 1.5671x over previous
//
#include <hip/hip_runtime.h>

#define D 64
#define IN 128
#define NEG_SLOPE 0.01f

// ---------------- Kernel 1: z = h @ fc_w^T, fused a_src/a_dst dots -----------
__global__ __launch_bounds__(256) void k_project(
    const float* __restrict__ h, const float* __restrict__ fc_w,
    const float* __restrict__ attn_w,
    float* __restrict__ z, float* __restrict__ a_src, float* __restrict__ a_dst,
    int n_nodes)
{
    __shared__ float w_lds[D][IN + 1];
    __shared__ float h_lds[4][IN];

    const int tid = threadIdx.x;
    for (int i = tid; i < D * IN; i += 256)
        w_lds[i / IN][i % IN] = fc_w[i];

    const int wave = tid >> 6;
    const int lane = tid & 63;
    const int node = blockIdx.x * 4 + wave;
    if (node < n_nodes) {
        h_lds[wave][lane]      = h[(size_t)node * IN + lane];
        h_lds[wave][lane + 64] = h[(size_t)node * IN + lane + 64];
    }
    __syncthreads();
    if (node >= n_nodes) return;

    float acc = 0.f;
    #pragma unroll
    for (int k = 0; k < IN; ++k)
        acc = fmaf(h_lds[wave][k], w_lds[lane][k], acc);

    z[(size_t)node * D + lane] = acc;

    float as = acc * attn_w[lane];
    float ad = acc * attn_w[D + lane];
    #pragma unroll
    for (int off = 32; off > 0; off >>= 1) {
        as += __shfl_xor(as, off, 64);
        ad += __shfl_xor(ad, off, 64);
    }
    if (lane == 0) { a_src[node] = as; a_dst[node] = ad; }
}

// ---------------- Kernel 2: degree histogram over dst ------------------------
__global__ __launch_bounds__(256) void k_hist(
    const int* __restrict__ dst, int* __restrict__ deg, int n_edges)
{
    int i = blockIdx.x * 256 + threadIdx.x;
    if (i >= n_edges) return;
    atomicAdd(&deg[dst[i]], 1);
}

// ---------------- Scan stage A: per-block sums (1024 nodes/block) ------------
__global__ __launch_bounds__(1024) void k_bsum(
    const int* __restrict__ deg, int* __restrict__ bsum, int n)
{
    __shared__ int ws[16];
    int i = blockIdx.x * 1024 + threadIdx.x;
    int v = (i < n) ? deg[i] : 0;
    #pragma unroll
    for (int o = 32; o > 0; o >>= 1) v += __shfl_xor(v, o, 64);
    if ((threadIdx.x & 63) == 0) ws[threadIdx.x >> 6] = v;
    __syncthreads();
    if (threadIdx.x < 16) {
        int s = ws[threadIdx.x];
        #pragma unroll
        for (int o = 8; o > 0; o >>= 1) s += __shfl_xor(s, o, 16);
        if (threadIdx.x == 0) bsum[blockIdx.x] = s;
    }
}

// ---------------- Scan stage B: exclusive scan of block sums (1 block) -------
__global__ __launch_bounds__(256) void k_scanb(int* __restrict__ bsum, int nb)
{
    __shared__ int lds[256];
    int t = threadIdx.x;
    int v = (t < nb) ? bsum[t] : 0;
    lds[t] = v;
    __syncthreads();
    for (int s = 1; s < 256; s <<= 1) {
        int u = (t >= s) ? lds[t - s] : 0;
        __syncthreads();
        lds[t] += u;
        __syncthreads();
    }
    if (t < nb) bsum[t] = lds[t] - v;   // exclusive
}

// ---------------- Scan stage C: local scan + block offset --------------------
__global__ __launch_bounds__(1024) void k_scanw(
    const int* __restrict__ deg, const int* __restrict__ bsum,
    int* __restrict__ off, int* __restrict__ cursor, int n)
{
    __shared__ int lds[1024];
    int t = threadIdx.x;
    int i = blockIdx.x * 1024 + t;
    int v = (i < n) ? deg[i] : 0;
    lds[t] = v;
    __syncthreads();
    for (int s = 1; s < 1024; s <<= 1) {
        int u = (t >= s) ? lds[t - s] : 0;
        __syncthreads();
        lds[t] += u;
        __syncthreads();
    }
    int ex = lds[t] - v + bsum[blockIdx.x];
    if (i < n) { off[i] = ex; cursor[i] = ex; }
    if (i == n - 1) off[n] = ex + v;
}

// ---------------- Kernel 4: fill buckets (CSR by dst) ------------------------
__global__ __launch_bounds__(256) void k_fill(
    const int* __restrict__ src, const int* __restrict__ dst,
    const float* __restrict__ a_src, const float* __restrict__ a_dst,
    int* __restrict__ cursor, float2* __restrict__ bucket, int n_edges)
{
    int i = blockIdx.x * 256 + threadIdx.x;
    if (i >= n_edges) return;
    int s = src[i], t = dst[i];
    float e = a_src[s] + a_dst[t];
    e = (e >= 0.f) ? e : NEG_SLOPE * e;
    int pos = atomicAdd(&cursor[t], 1);
    bucket[pos] = make_float2(e, __int_as_float(s));
}

// ---------------- Kernel 5: per-node softmax + weighted gather ---------------
__global__ __launch_bounds__(256) void k_node(
    const int* __restrict__ off, const float2* __restrict__ bucket,
    const float* __restrict__ z, float* __restrict__ out, int n_nodes)
{
    int node = blockIdx.x * 4 + (threadIdx.x >> 6);
    if (node >= n_nodes) return;
    int lane = threadIdx.x & 63;
    int beg = off[node], end = off[node + 1];

    float m = -INFINITY;
    for (int j = beg; j < end; ++j)
        m = fmaxf(m, bucket[j].x);

    float den = 0.f, acc = 0.f;
    for (int j = beg; j < end; ++j) {
        float2 b = bucket[j];
        float w = __expf(b.x - m);
        den += w;
        int s = __float_as_int(b.y);
        acc = fmaf(w, z[(size_t)s * D + lane], acc);
    }
    out[(size_t)node * D + lane] = (end > beg) ? acc / den : 0.f;
}

extern "C" void kernel_launch(void* const* d_in, const int* in_sizes, int n_in,
                              void* d_out, int out_size, void* d_ws, size_t ws_size,
                              hipStream_t stream) {
    const float* h      = (const float*)d_in[0];
    const int*   src    = (const int*)d_in[1];
    const int*   dst    = (const int*)d_in[2];
    const float* fc_w   = (const float*)d_in[3];
    const float* attn_w = (const float*)d_in[4];

    const int n_nodes = in_sizes[0] / IN;
    const int n_edges = in_sizes[1];
    float* out = (float*)d_out;

    const int nb = (n_nodes + 1023) / 1024;   // 98 for N=100k (must be <=256)

    // workspace layout
    char* p = (char*)d_ws;
    float*  z      = (float*)p;  p += (size_t)n_nodes * D * sizeof(float);
    float*  a_src  = (float*)p;  p += (size_t)n_nodes * sizeof(float);
    float*  a_dst  = (float*)p;  p += (size_t)n_nodes * sizeof(float);
    int*    deg    = (int*)p;    p += (size_t)n_nodes * sizeof(int);
    int*    off    = (int*)p;    p += ((size_t)n_nodes + 1) * sizeof(int);
    int*    cursor = (int*)p;    p += (size_t)n_nodes * sizeof(int);
    int*    bsum   = (int*)p;    p += 256 * sizeof(int);
    float2* bucket = (float2*)p; p += (size_t)n_edges * sizeof(float2);

    hipMemsetAsync(deg, 0, (size_t)n_nodes * sizeof(int), stream);

    k_project<<<dim3((n_nodes + 3) / 4), dim3(256), 0, stream>>>(
        h, fc_w, attn_w, z, a_src, a_dst, n_nodes);
    k_hist<<<dim3((n_edges + 255) / 256), dim3(256), 0, stream>>>(
        dst, deg, n_edges);
    k_bsum<<<dim3(nb), dim3(1024), 0, stream>>>(deg, bsum, n_nodes);
    k_scanb<<<dim3(1), dim3(256), 0, stream>>>(bsum, nb);
    k_scanw<<<dim3(nb), dim3(1024), 0, stream>>>(deg, bsum, off, cursor, n_nodes);
    k_fill<<<dim3((n_edges + 255) / 256), dim3(256), 0, stream>>>(
        src, dst, a_src, a_dst, cursor, bucket, n_edges);
    k_node<<<dim3((n_nodes + 3) / 4), dim3(256), 0, stream>>>(
        off, bucket, z, out, n_nodes);
}

// Round 4
// 340.863 us; speedup vs baseline: 2.0756x; 1.3245x over previous
//
#include <hip/hip_runtime.h>

#define D 64
#define IN 128
#define NEG_SLOPE 0.01f

// ---------------- Kernel 1: z = h @ fc_w^T, fused a_src/a_dst dots -----------
__global__ __launch_bounds__(256) void k_project(
    const float* __restrict__ h, const float* __restrict__ fc_w,
    const float* __restrict__ attn_w,
    float* __restrict__ z, float* __restrict__ a_src, float* __restrict__ a_dst,
    int n_nodes)
{
    __shared__ float w_lds[D][IN + 1];
    __shared__ float h_lds[4][IN];

    const int tid = threadIdx.x;
    for (int i = tid; i < D * IN; i += 256)
        w_lds[i / IN][i % IN] = fc_w[i];

    const int wave = tid >> 6;
    const int lane = tid & 63;
    const int node = blockIdx.x * 4 + wave;
    if (node < n_nodes) {
        h_lds[wave][lane]      = h[(size_t)node * IN + lane];
        h_lds[wave][lane + 64] = h[(size_t)node * IN + lane + 64];
    }
    __syncthreads();
    if (node >= n_nodes) return;

    float acc = 0.f;
    #pragma unroll
    for (int k = 0; k < IN; ++k)
        acc = fmaf(h_lds[wave][k], w_lds[lane][k], acc);

    z[(size_t)node * D + lane] = acc;

    float as = acc * attn_w[lane];
    float ad = acc * attn_w[D + lane];
    #pragma unroll
    for (int off = 32; off > 0; off >>= 1) {
        as += __shfl_xor(as, off, 64);
        ad += __shfl_xor(ad, off, 64);
    }
    if (lane == 0) { a_src[node] = as; a_dst[node] = ad; }
}

// ---------------- Kernel 2: degree histogram over dst ------------------------
__global__ __launch_bounds__(256) void k_hist(
    const int* __restrict__ dst, int* __restrict__ deg, int n_edges)
{
    int i = blockIdx.x * 256 + threadIdx.x;
    if (i >= n_edges) return;
    atomicAdd(&deg[dst[i]], 1);
}

// ---------------- Scan stage A: per-block sums (1024 nodes/block) ------------
__global__ __launch_bounds__(1024) void k_bsum(
    const int* __restrict__ deg, int* __restrict__ bsum, int n)
{
    __shared__ int ws[16];
    int i = blockIdx.x * 1024 + threadIdx.x;
    int v = (i < n) ? deg[i] : 0;
    #pragma unroll
    for (int o = 32; o > 0; o >>= 1) v += __shfl_xor(v, o, 64);
    if ((threadIdx.x & 63) == 0) ws[threadIdx.x >> 6] = v;
    __syncthreads();
    if (threadIdx.x < 16) {
        int s = ws[threadIdx.x];
        #pragma unroll
        for (int o = 8; o > 0; o >>= 1) s += __shfl_xor(s, o, 16);
        if (threadIdx.x == 0) bsum[blockIdx.x] = s;
    }
}

// ---------------- Scan stage B: exclusive scan of block sums (1 block) -------
__global__ __launch_bounds__(256) void k_scanb(int* __restrict__ bsum, int nb)
{
    __shared__ int lds[256];
    int t = threadIdx.x;
    int v = (t < nb) ? bsum[t] : 0;
    lds[t] = v;
    __syncthreads();
    for (int s = 1; s < 256; s <<= 1) {
        int u = (t >= s) ? lds[t - s] : 0;
        __syncthreads();
        lds[t] += u;
        __syncthreads();
    }
    if (t < nb) bsum[t] = lds[t] - v;   // exclusive
}

// ---------------- Scan stage C: local scan + block offset --------------------
__global__ __launch_bounds__(1024) void k_scanw(
    const int* __restrict__ deg, const int* __restrict__ bsum,
    int* __restrict__ off, int* __restrict__ cursor, int n)
{
    __shared__ int lds[1024];
    int t = threadIdx.x;
    int i = blockIdx.x * 1024 + t;
    int v = (i < n) ? deg[i] : 0;
    lds[t] = v;
    __syncthreads();
    for (int s = 1; s < 1024; s <<= 1) {
        int u = (t >= s) ? lds[t - s] : 0;
        __syncthreads();
        lds[t] += u;
        __syncthreads();
    }
    int ex = lds[t] - v + bsum[blockIdx.x];
    if (i < n) { off[i] = ex; cursor[i] = ex; }
    if (i == n - 1) off[n] = ex + v;
}

// ---------------- Kernel 4: fill buckets (CSR by dst) ------------------------
__global__ __launch_bounds__(256) void k_fill(
    const int* __restrict__ src, const int* __restrict__ dst,
    const float* __restrict__ a_src, const float* __restrict__ a_dst,
    int* __restrict__ cursor, float2* __restrict__ bucket, int n_edges)
{
    int i = blockIdx.x * 256 + threadIdx.x;
    if (i >= n_edges) return;
    int s = src[i], t = dst[i];
    float e = a_src[s] + a_dst[t];
    e = (e >= 0.f) ? e : NEG_SLOPE * e;
    int pos = atomicAdd(&cursor[t], 1);
    bucket[pos] = make_float2(e, __int_as_float(s));
}

// ---------------- Kernel 5: per-node softmax + weighted gather ---------------
// one wave per node; wave-cooperative softmax, 4 edges/iter vectorized gather
__global__ __launch_bounds__(256) void k_node(
    const int* __restrict__ off, const float2* __restrict__ bucket,
    const float4* __restrict__ z4, float4* __restrict__ out4, int n_nodes)
{
    int node = blockIdx.x * 4 + (threadIdx.x >> 6);
    if (node >= n_nodes) return;
    const int lane = threadIdx.x & 63;
    const int q    = lane >> 4;    // edge slot within group-of-4
    const int l16  = lane & 15;    // float4 column within z-row
    int beg = off[node], end = off[node + 1];
    int deg = end - beg;

    float den = 0.f;
    float4 acc = make_float4(0.f, 0.f, 0.f, 0.f);

    if (deg <= 64) {
        // fast path: whole segment lives in one per-lane chunk
        int j = beg + lane;
        float e = -INFINITY; int sl = 0;
        if (j < end) {
            float2 b = bucket[j];
            e = b.x; sl = __float_as_int(b.y);
        }
        float m = e;
        #pragma unroll
        for (int o = 32; o > 0; o >>= 1) m = fmaxf(m, __shfl_xor(m, o, 64));
        float ex = (j < end) ? __expf(e - m) : 0.f;
        float exs = ex;
        #pragma unroll
        for (int o = 32; o > 0; o >>= 1) exs += __shfl_xor(exs, o, 64);
        den = exs;

        int ng = (deg + 3) >> 2;
        for (int g = 0; g < ng; ++g) {
            float w = __shfl(ex, g * 4 + q, 64);
            int   s = __shfl(sl, g * 4 + q, 64);
            float4 zr = z4[(size_t)s * 16 + l16];
            acc.x = fmaf(w, zr.x, acc.x);
            acc.y = fmaf(w, zr.y, acc.y);
            acc.z = fmaf(w, zr.z, acc.z);
            acc.w = fmaf(w, zr.w, acc.w);
        }
    } else {
        // general chunked path (rare: deg > 64)
        float m = -INFINITY;
        for (int c = beg; c < end; c += 64) {
            int j = c + lane;
            float e = (j < end) ? bucket[j].x : -INFINITY;
            m = fmaxf(m, e);
        }
        #pragma unroll
        for (int o = 32; o > 0; o >>= 1) m = fmaxf(m, __shfl_xor(m, o, 64));

        for (int c = beg; c < end; c += 64) {
            int j = c + lane;
            float ex = 0.f; int sl = 0;
            if (j < end) {
                float2 b = bucket[j];
                ex = __expf(b.x - m);
                sl = __float_as_int(b.y);
            }
            float exs = ex;
            #pragma unroll
            for (int o = 32; o > 0; o >>= 1) exs += __shfl_xor(exs, o, 64);
            den += exs;

            int lim = end - c; if (lim > 64) lim = 64;
            int ng = (lim + 3) >> 2;
            for (int g = 0; g < ng; ++g) {
                float w = __shfl(ex, g * 4 + q, 64);
                int   s = __shfl(sl, g * 4 + q, 64);
                float4 zr = z4[(size_t)s * 16 + l16];
                acc.x = fmaf(w, zr.x, acc.x);
                acc.y = fmaf(w, zr.y, acc.y);
                acc.z = fmaf(w, zr.z, acc.z);
                acc.w = fmaf(w, zr.w, acc.w);
            }
        }
    }

    // reduce the 4 edge-groups (lanes differing in bits 4..5 hold partials of same dims)
    #pragma unroll
    for (int o = 16; o <= 32; o <<= 1) {
        acc.x += __shfl_xor(acc.x, o, 64);
        acc.y += __shfl_xor(acc.y, o, 64);
        acc.z += __shfl_xor(acc.z, o, 64);
        acc.w += __shfl_xor(acc.w, o, 64);
    }

    if (lane < 16) {
        float inv = (deg > 0) ? 1.f / den : 0.f;
        float4 o4 = make_float4(acc.x * inv, acc.y * inv, acc.z * inv, acc.w * inv);
        out4[(size_t)node * 16 + l16] = o4;
    }
}

extern "C" void kernel_launch(void* const* d_in, const int* in_sizes, int n_in,
                              void* d_out, int out_size, void* d_ws, size_t ws_size,
                              hipStream_t stream) {
    const float* h      = (const float*)d_in[0];
    const int*   src    = (const int*)d_in[1];
    const int*   dst    = (const int*)d_in[2];
    const float* fc_w   = (const float*)d_in[3];
    const float* attn_w = (const float*)d_in[4];

    const int n_nodes = in_sizes[0] / IN;
    const int n_edges = in_sizes[1];
    float* out = (float*)d_out;

    const int nb = (n_nodes + 1023) / 1024;   // 98 for N=100k (must be <=256)

    // workspace layout
    char* p = (char*)d_ws;
    float*  z      = (float*)p;  p += (size_t)n_nodes * D * sizeof(float);
    float*  a_src  = (float*)p;  p += (size_t)n_nodes * sizeof(float);
    float*  a_dst  = (float*)p;  p += (size_t)n_nodes * sizeof(float);
    int*    deg    = (int*)p;    p += (size_t)n_nodes * sizeof(int);
    int*    off    = (int*)p;    p += ((size_t)n_nodes + 1) * sizeof(int);
    int*    cursor = (int*)p;    p += (size_t)n_nodes * sizeof(int);
    int*    bsum   = (int*)p;    p += 256 * sizeof(int);
    float2* bucket = (float2*)p; p += (size_t)n_edges * sizeof(float2);

    hipMemsetAsync(deg, 0, (size_t)n_nodes * sizeof(int), stream);

    k_project<<<dim3((n_nodes + 3) / 4), dim3(256), 0, stream>>>(
        h, fc_w, attn_w, z, a_src, a_dst, n_nodes);
    k_hist<<<dim3((n_edges + 255) / 256), dim3(256), 0, stream>>>(
        dst, deg, n_edges);
    k_bsum<<<dim3(nb), dim3(1024), 0, stream>>>(deg, bsum, n_nodes);
    k_scanb<<<dim3(1), dim3(256), 0, stream>>>(bsum, nb);
    k_scanw<<<dim3(nb), dim3(1024), 0, stream>>>(deg, bsum, off, cursor, n_nodes);
    k_fill<<<dim3((n_edges + 255) / 256), dim3(256), 0, stream>>>(
        src, dst, a_src, a_dst, cursor, bucket, n_edges);
    k_node<<<dim3((n_nodes + 3) / 4), dim3(256), 0, stream>>>(
        off, bucket, (const float4*)z, (float4*)out, n_nodes);
}

// Round 5
// 256.945 us; speedup vs baseline: 2.7534x; 1.3266x over previous
//
#include <hip/hip_runtime.h>

#define D 64
#define IN 128
#define NEG_SLOPE 0.01f

using f32x4  = __attribute__((ext_vector_type(4))) float;
using bf16x8 = __attribute__((ext_vector_type(8))) short;   // 8 bf16 in 4 VGPRs

__device__ __forceinline__ short f2bf(float f) {
    unsigned u = __float_as_uint(f);
    u = u + 0x7FFFu + ((u >> 16) & 1u);   // RNE to bf16
    return (short)(u >> 16);
}

// ---------------- Kernel 1: z = h @ fc_w^T via MFMA, fused a_src/a_dst ------
// one wave per 16 nodes; B-frags (fc_w) persistent in VGPRs; no LDS
__global__ __launch_bounds__(256) void k_project(
    const float* __restrict__ h, const float* __restrict__ fc_w,
    const float* __restrict__ attn_w,
    float* __restrict__ z, float* __restrict__ a_src, float* __restrict__ a_dst,
    int n_nodes)
{
    const int wid  = threadIdx.x >> 6;
    const int lane = threadIdx.x & 63;
    const int g16  = lane >> 4;    // 0..3 : k-chunk / row-group selector
    const int l16  = lane & 15;    // 0..15: row (A/B) or col (C/D)
    const int base = (blockIdx.x * 4 + wid) * 16;
    if (base >= n_nodes) return;   // n_nodes % 16 == 0 -> wave all-or-nothing

    // ---- B fragments: B[k][n] = fc_w[n][k]; lane holds col=l16(+16t), k=g16*8+j
    bf16x8 bfrag[4][4];            // [col-tile][k-step]
    #pragma unroll
    for (int t = 0; t < 4; ++t) {
        const float* wrow = fc_w + (size_t)(t * 16 + l16) * IN + g16 * 8;
        #pragma unroll
        for (int ks = 0; ks < 4; ++ks) {
            f32x4 w0 = *(const f32x4*)(wrow + ks * 32);
            f32x4 w1 = *(const f32x4*)(wrow + ks * 32 + 4);
            bf16x8 b;
            b[0] = f2bf(w0[0]); b[1] = f2bf(w0[1]); b[2] = f2bf(w0[2]); b[3] = f2bf(w0[3]);
            b[4] = f2bf(w1[0]); b[5] = f2bf(w1[1]); b[6] = f2bf(w1[2]); b[7] = f2bf(w1[3]);
            bfrag[t][ks] = b;
        }
    }

    // ---- A fragments: lane holds row=l16, k=g16*8+j (+32*ks) -> 32B contiguous
    const float* hrow = h + (size_t)(base + l16) * IN + g16 * 8;
    bf16x8 afrag[4];
    #pragma unroll
    for (int ks = 0; ks < 4; ++ks) {
        f32x4 h0 = *(const f32x4*)(hrow + ks * 32);
        f32x4 h1 = *(const f32x4*)(hrow + ks * 32 + 4);
        bf16x8 a;
        a[0] = f2bf(h0[0]); a[1] = f2bf(h0[1]); a[2] = f2bf(h0[2]); a[3] = f2bf(h0[3]);
        a[4] = f2bf(h1[0]); a[5] = f2bf(h1[1]); a[6] = f2bf(h1[2]); a[7] = f2bf(h1[3]);
        afrag[ks] = a;
    }

    f32x4 acc[4] = {f32x4{0,0,0,0}, f32x4{0,0,0,0}, f32x4{0,0,0,0}, f32x4{0,0,0,0}};
    #pragma unroll
    for (int t = 0; t < 4; ++t)
        #pragma unroll
        for (int ks = 0; ks < 4; ++ks)
            acc[t] = __builtin_amdgcn_mfma_f32_16x16x32_bf16(
                afrag[ks], bfrag[t][ks], acc[t], 0, 0, 0);

    // ---- store z: D layout col = t*16+l16, row(node) = base + g16*4 + r -----
    #pragma unroll
    for (int t = 0; t < 4; ++t)
        #pragma unroll
        for (int r = 0; r < 4; ++r)
            z[(size_t)(base + g16 * 4 + r) * D + t * 16 + l16] = acc[t][r];

    // ---- a_src/a_dst: per-row dot with attn_w over the 64 cols --------------
    float awx[4], awy[4];
    #pragma unroll
    for (int t = 0; t < 4; ++t) {
        awx[t] = attn_w[t * 16 + l16];
        awy[t] = attn_w[D + t * 16 + l16];
    }
    #pragma unroll
    for (int r = 0; r < 4; ++r) {
        float as = acc[0][r] * awx[0] + acc[1][r] * awx[1]
                 + acc[2][r] * awx[2] + acc[3][r] * awx[3];
        float ad = acc[0][r] * awy[0] + acc[1][r] * awy[1]
                 + acc[2][r] * awy[2] + acc[3][r] * awy[3];
        #pragma unroll
        for (int o = 1; o < 16; o <<= 1) {
            as += __shfl_xor(as, o, 64);
            ad += __shfl_xor(ad, o, 64);
        }
        if (l16 == 0) {
            a_src[base + g16 * 4 + r] = as;
            a_dst[base + g16 * 4 + r] = ad;
        }
    }
}

// ---------------- Kernel 2: degree histogram over dst ------------------------
__global__ __launch_bounds__(256) void k_hist(
    const int* __restrict__ dst, int* __restrict__ deg, int n_edges)
{
    int i = blockIdx.x * 256 + threadIdx.x;
    if (i >= n_edges) return;
    atomicAdd(&deg[dst[i]], 1);
}

// ---------------- Scan stage A: per-block sums (1024 nodes/block) ------------
__global__ __launch_bounds__(1024) void k_bsum(
    const int* __restrict__ deg, int* __restrict__ bsum, int n)
{
    __shared__ int ws[16];
    int i = blockIdx.x * 1024 + threadIdx.x;
    int v = (i < n) ? deg[i] : 0;
    #pragma unroll
    for (int o = 32; o > 0; o >>= 1) v += __shfl_xor(v, o, 64);
    if ((threadIdx.x & 63) == 0) ws[threadIdx.x >> 6] = v;
    __syncthreads();
    if (threadIdx.x < 16) {
        int s = ws[threadIdx.x];
        #pragma unroll
        for (int o = 8; o > 0; o >>= 1) s += __shfl_xor(s, o, 16);
        if (threadIdx.x == 0) bsum[blockIdx.x] = s;
    }
}

// ---------------- Scan stage B: exclusive scan of block sums (1 block) -------
__global__ __launch_bounds__(256) void k_scanb(int* __restrict__ bsum, int nb)
{
    __shared__ int lds[256];
    int t = threadIdx.x;
    int v = (t < nb) ? bsum[t] : 0;
    lds[t] = v;
    __syncthreads();
    for (int s = 1; s < 256; s <<= 1) {
        int u = (t >= s) ? lds[t - s] : 0;
        __syncthreads();
        lds[t] += u;
        __syncthreads();
    }
    if (t < nb) bsum[t] = lds[t] - v;   // exclusive
}

// ---------------- Scan stage C: local scan + block offset --------------------
__global__ __launch_bounds__(1024) void k_scanw(
    const int* __restrict__ deg, const int* __restrict__ bsum,
    int* __restrict__ off, int* __restrict__ cursor, int n)
{
    __shared__ int lds[1024];
    int t = threadIdx.x;
    int i = blockIdx.x * 1024 + t;
    int v = (i < n) ? deg[i] : 0;
    lds[t] = v;
    __syncthreads();
    for (int s = 1; s < 1024; s <<= 1) {
        int u = (t >= s) ? lds[t - s] : 0;
        __syncthreads();
        lds[t] += u;
        __syncthreads();
    }
    int ex = lds[t] - v + bsum[blockIdx.x];
    if (i < n) { off[i] = ex; cursor[i] = ex; }
    if (i == n - 1) off[n] = ex + v;
}

// ---------------- Kernel 4: fill buckets (CSR by dst) ------------------------
__global__ __launch_bounds__(256) void k_fill(
    const int* __restrict__ src, const int* __restrict__ dst,
    const float* __restrict__ a_src, const float* __restrict__ a_dst,
    int* __restrict__ cursor, float2* __restrict__ bucket, int n_edges)
{
    int i = blockIdx.x * 256 + threadIdx.x;
    if (i >= n_edges) return;
    int s = src[i], t = dst[i];
    float e = a_src[s] + a_dst[t];
    e = (e >= 0.f) ? e : NEG_SLOPE * e;
    int pos = atomicAdd(&cursor[t], 1);
    bucket[pos] = make_float2(e, __int_as_float(s));
}

// ---------------- Kernel 5: per-node softmax + weighted gather ---------------
__global__ __launch_bounds__(256) void k_node(
    const int* __restrict__ off, const float2* __restrict__ bucket,
    const float4* __restrict__ z4, float4* __restrict__ out4, int n_nodes)
{
    int node = blockIdx.x * 4 + (threadIdx.x >> 6);
    if (node >= n_nodes) return;
    const int lane = threadIdx.x & 63;
    const int q    = lane >> 4;
    const int l16  = lane & 15;
    int beg = off[node], end = off[node + 1];
    int deg = end - beg;

    float den = 0.f;
    float4 acc = make_float4(0.f, 0.f, 0.f, 0.f);

    if (deg <= 64) {
        int j = beg + lane;
        float e = -INFINITY; int sl = 0;
        if (j < end) {
            float2 b = bucket[j];
            e = b.x; sl = __float_as_int(b.y);
        }
        float m = e;
        #pragma unroll
        for (int o = 32; o > 0; o >>= 1) m = fmaxf(m, __shfl_xor(m, o, 64));
        float ex = (j < end) ? __expf(e - m) : 0.f;
        float exs = ex;
        #pragma unroll
        for (int o = 32; o > 0; o >>= 1) exs += __shfl_xor(exs, o, 64);
        den = exs;

        int ng = (deg + 3) >> 2;
        for (int g = 0; g < ng; ++g) {
            float w = __shfl(ex, g * 4 + q, 64);
            int   s = __shfl(sl, g * 4 + q, 64);
            float4 zr = z4[(size_t)s * 16 + l16];
            acc.x = fmaf(w, zr.x, acc.x);
            acc.y = fmaf(w, zr.y, acc.y);
            acc.z = fmaf(w, zr.z, acc.z);
            acc.w = fmaf(w, zr.w, acc.w);
        }
    } else {
        float m = -INFINITY;
        for (int c = beg; c < end; c += 64) {
            int j = c + lane;
            float e = (j < end) ? bucket[j].x : -INFINITY;
            m = fmaxf(m, e);
        }
        #pragma unroll
        for (int o = 32; o > 0; o >>= 1) m = fmaxf(m, __shfl_xor(m, o, 64));

        for (int c = beg; c < end; c += 64) {
            int j = c + lane;
            float ex = 0.f; int sl = 0;
            if (j < end) {
                float2 b = bucket[j];
                ex = __expf(b.x - m);
                sl = __float_as_int(b.y);
            }
            float exs = ex;
            #pragma unroll
            for (int o = 32; o > 0; o >>= 1) exs += __shfl_xor(exs, o, 64);
            den += exs;

            int lim = end - c; if (lim > 64) lim = 64;
            int ng = (lim + 3) >> 2;
            for (int g = 0; g < ng; ++g) {
                float w = __shfl(ex, g * 4 + q, 64);
                int   s = __shfl(sl, g * 4 + q, 64);
                float4 zr = z4[(size_t)s * 16 + l16];
                acc.x = fmaf(w, zr.x, acc.x);
                acc.y = fmaf(w, zr.y, acc.y);
                acc.z = fmaf(w, zr.z, acc.z);
                acc.w = fmaf(w, zr.w, acc.w);
            }
        }
    }

    #pragma unroll
    for (int o = 16; o <= 32; o <<= 1) {
        acc.x += __shfl_xor(acc.x, o, 64);
        acc.y += __shfl_xor(acc.y, o, 64);
        acc.z += __shfl_xor(acc.z, o, 64);
        acc.w += __shfl_xor(acc.w, o, 64);
    }

    if (lane < 16) {
        float inv = (deg > 0) ? 1.f / den : 0.f;
        float4 o4 = make_float4(acc.x * inv, acc.y * inv, acc.z * inv, acc.w * inv);
        out4[(size_t)node * 16 + l16] = o4;
    }
}

extern "C" void kernel_launch(void* const* d_in, const int* in_sizes, int n_in,
                              void* d_out, int out_size, void* d_ws, size_t ws_size,
                              hipStream_t stream) {
    const float* h      = (const float*)d_in[0];
    const int*   src    = (const int*)d_in[1];
    const int*   dst    = (const int*)d_in[2];
    const float* fc_w   = (const float*)d_in[3];
    const float* attn_w = (const float*)d_in[4];

    const int n_nodes = in_sizes[0] / IN;
    const int n_edges = in_sizes[1];
    float* out = (float*)d_out;

    const int nb = (n_nodes + 1023) / 1024;   // 98 for N=100k (must be <=256)

    // workspace layout
    char* p = (char*)d_ws;
    float*  z      = (float*)p;  p += (size_t)n_nodes * D * sizeof(float);
    float*  a_src  = (float*)p;  p += (size_t)n_nodes * sizeof(float);
    float*  a_dst  = (float*)p;  p += (size_t)n_nodes * sizeof(float);
    int*    deg    = (int*)p;    p += (size_t)n_nodes * sizeof(int);
    int*    off    = (int*)p;    p += ((size_t)n_nodes + 1) * sizeof(int);
    int*    cursor = (int*)p;    p += (size_t)n_nodes * sizeof(int);
    int*    bsum   = (int*)p;    p += 256 * sizeof(int);
    float2* bucket = (float2*)p; p += (size_t)n_edges * sizeof(float2);

    hipMemsetAsync(deg, 0, (size_t)n_nodes * sizeof(int), stream);

    k_project<<<dim3((n_nodes + 63) / 64), dim3(256), 0, stream>>>(
        h, fc_w, attn_w, z, a_src, a_dst, n_nodes);
    k_hist<<<dim3((n_edges + 255) / 256), dim3(256), 0, stream>>>(
        dst, deg, n_edges);
    k_bsum<<<dim3(nb), dim3(1024), 0, stream>>>(deg, bsum, n_nodes);
    k_scanb<<<dim3(1), dim3(256), 0, stream>>>(bsum, nb);
    k_scanw<<<dim3(nb), dim3(1024), 0, stream>>>(deg, bsum, off, cursor, n_nodes);
    k_fill<<<dim3((n_edges + 255) / 256), dim3(256), 0, stream>>>(
        src, dst, a_src, a_dst, cursor, bucket, n_edges);
    k_node<<<dim3((n_nodes + 3) / 4), dim3(256), 0, stream>>>(
        off, bucket, (const float4*)z, (float4*)out, n_nodes);
}

// Round 6
// 252.332 us; speedup vs baseline: 2.8038x; 1.0183x over previous
//
#include <hip/hip_runtime.h>

#define D 64
#define IN 128
#define NEG_SLOPE 0.01f

using f32x4  = __attribute__((ext_vector_type(4))) float;
using bf16x8 = __attribute__((ext_vector_type(8))) short;   // 8 bf16 in 4 VGPRs

__device__ __forceinline__ short f2bf(float f) {
    unsigned u = __float_as_uint(f);
    u = u + 0x7FFFu + ((u >> 16) & 1u);   // RNE to bf16
    return (short)(u >> 16);
}

// ---------------- Kernel 1: z = h @ fc_w^T via MFMA, fused a_src/a_dst ------
__global__ __launch_bounds__(256) void k_project(
    const float* __restrict__ h, const float* __restrict__ fc_w,
    const float* __restrict__ attn_w,
    float* __restrict__ z, float* __restrict__ a_src, float* __restrict__ a_dst,
    int n_nodes)
{
    const int wid  = threadIdx.x >> 6;
    const int lane = threadIdx.x & 63;
    const int g16  = lane >> 4;
    const int l16  = lane & 15;
    const int base = (blockIdx.x * 4 + wid) * 16;
    if (base >= n_nodes) return;

    bf16x8 bfrag[4][4];
    #pragma unroll
    for (int t = 0; t < 4; ++t) {
        const float* wrow = fc_w + (size_t)(t * 16 + l16) * IN + g16 * 8;
        #pragma unroll
        for (int ks = 0; ks < 4; ++ks) {
            f32x4 w0 = *(const f32x4*)(wrow + ks * 32);
            f32x4 w1 = *(const f32x4*)(wrow + ks * 32 + 4);
            bf16x8 b;
            b[0] = f2bf(w0[0]); b[1] = f2bf(w0[1]); b[2] = f2bf(w0[2]); b[3] = f2bf(w0[3]);
            b[4] = f2bf(w1[0]); b[5] = f2bf(w1[1]); b[6] = f2bf(w1[2]); b[7] = f2bf(w1[3]);
            bfrag[t][ks] = b;
        }
    }

    const float* hrow = h + (size_t)(base + l16) * IN + g16 * 8;
    bf16x8 afrag[4];
    #pragma unroll
    for (int ks = 0; ks < 4; ++ks) {
        f32x4 h0 = *(const f32x4*)(hrow + ks * 32);
        f32x4 h1 = *(const f32x4*)(hrow + ks * 32 + 4);
        bf16x8 a;
        a[0] = f2bf(h0[0]); a[1] = f2bf(h0[1]); a[2] = f2bf(h0[2]); a[3] = f2bf(h0[3]);
        a[4] = f2bf(h1[0]); a[5] = f2bf(h1[1]); a[6] = f2bf(h1[2]); a[7] = f2bf(h1[3]);
        afrag[ks] = a;
    }

    f32x4 acc[4] = {f32x4{0,0,0,0}, f32x4{0,0,0,0}, f32x4{0,0,0,0}, f32x4{0,0,0,0}};
    #pragma unroll
    for (int t = 0; t < 4; ++t)
        #pragma unroll
        for (int ks = 0; ks < 4; ++ks)
            acc[t] = __builtin_amdgcn_mfma_f32_16x16x32_bf16(
                afrag[ks], bfrag[t][ks], acc[t], 0, 0, 0);

    #pragma unroll
    for (int t = 0; t < 4; ++t)
        #pragma unroll
        for (int r = 0; r < 4; ++r)
            z[(size_t)(base + g16 * 4 + r) * D + t * 16 + l16] = acc[t][r];

    float awx[4], awy[4];
    #pragma unroll
    for (int t = 0; t < 4; ++t) {
        awx[t] = attn_w[t * 16 + l16];
        awy[t] = attn_w[D + t * 16 + l16];
    }
    #pragma unroll
    for (int r = 0; r < 4; ++r) {
        float as = acc[0][r] * awx[0] + acc[1][r] * awx[1]
                 + acc[2][r] * awx[2] + acc[3][r] * awx[3];
        float ad = acc[0][r] * awy[0] + acc[1][r] * awy[1]
                 + acc[2][r] * awy[2] + acc[3][r] * awy[3];
        #pragma unroll
        for (int o = 1; o < 16; o <<= 1) {
            as += __shfl_xor(as, o, 64);
            ad += __shfl_xor(ad, o, 64);
        }
        if (l16 == 0) {
            a_src[base + g16 * 4 + r] = as;
            a_dst[base + g16 * 4 + r] = ad;
        }
    }
}

// ---------------- Kernel 2: degree histogram over dst ------------------------
__global__ __launch_bounds__(256) void k_hist(
    const int* __restrict__ dst, int* __restrict__ deg, int n_edges)
{
    int i = blockIdx.x * 256 + threadIdx.x;
    if (i >= n_edges) return;
    atomicAdd(&deg[dst[i]], 1);
}

// ---------------- Scan stage A: per-block sums (1024 nodes/block) ------------
__global__ __launch_bounds__(1024) void k_bsum(
    const int* __restrict__ deg, int* __restrict__ bsum, int n)
{
    __shared__ int ws[16];
    int i = blockIdx.x * 1024 + threadIdx.x;
    int v = (i < n) ? deg[i] : 0;
    #pragma unroll
    for (int o = 32; o > 0; o >>= 1) v += __shfl_xor(v, o, 64);
    if ((threadIdx.x & 63) == 0) ws[threadIdx.x >> 6] = v;
    __syncthreads();
    if (threadIdx.x < 16) {
        int s = ws[threadIdx.x];
        #pragma unroll
        for (int o = 8; o > 0; o >>= 1) s += __shfl_xor(s, o, 16);
        if (threadIdx.x == 0) bsum[blockIdx.x] = s;
    }
}

// ---------------- Scan stage B: exclusive scan of block sums (1 block) -------
__global__ __launch_bounds__(256) void k_scanb(int* __restrict__ bsum, int nb)
{
    __shared__ int lds[256];
    int t = threadIdx.x;
    int v = (t < nb) ? bsum[t] : 0;
    lds[t] = v;
    __syncthreads();
    for (int s = 1; s < 256; s <<= 1) {
        int u = (t >= s) ? lds[t - s] : 0;
        __syncthreads();
        lds[t] += u;
        __syncthreads();
    }
    if (t < nb) bsum[t] = lds[t] - v;
}

// ---------------- Scan stage C: local scan + block offset --------------------
__global__ __launch_bounds__(1024) void k_scanw(
    const int* __restrict__ deg, const int* __restrict__ bsum,
    int* __restrict__ off, int* __restrict__ cursor, int n)
{
    __shared__ int lds[1024];
    int t = threadIdx.x;
    int i = blockIdx.x * 1024 + t;
    int v = (i < n) ? deg[i] : 0;
    lds[t] = v;
    __syncthreads();
    for (int s = 1; s < 1024; s <<= 1) {
        int u = (t >= s) ? lds[t - s] : 0;
        __syncthreads();
        lds[t] += u;
        __syncthreads();
    }
    int ex = lds[t] - v + bsum[blockIdx.x];
    if (i < n) { off[i] = ex; cursor[i] = ex; }
    if (i == n - 1) off[n] = ex + v;
}

// ---------------- Kernel 4: XCD-sliced CSR fill -------------------------------
// slice = blockIdx&7 -> XCD (round-robin dispatch). Each slice streams the full
// dst array but only handles its 1/8 node range: cursor atomics + bucket stores
// stay L2-local to one XCD -> full-line evictions instead of partial-line bounce.
__global__ __launch_bounds__(256) void k_fill(
    const int* __restrict__ src, const int* __restrict__ dst,
    int* __restrict__ cursor, int* __restrict__ bucket,
    int n_edges, int nodes_per_slice, int n_nodes, int edges_per_block)
{
    const int slice = blockIdx.x & 7;
    const int chunk = blockIdx.x >> 3;
    const int lo = slice * nodes_per_slice;
    const int hi = min(lo + nodes_per_slice, n_nodes);
    const int e1 = min((chunk + 1) * edges_per_block, n_edges);
    for (int i = chunk * edges_per_block + threadIdx.x; i < e1; i += 256) {
        int t = dst[i];
        if (t >= lo && t < hi) {
            int s = src[i];
            int pos = atomicAdd(&cursor[t], 1);
            bucket[pos] = s;
        }
    }
}

// ---------------- Kernel 5: per-node softmax + weighted gather ---------------
__global__ __launch_bounds__(256) void k_node(
    const int* __restrict__ off, const int* __restrict__ bucket,
    const float* __restrict__ a_src, const float* __restrict__ a_dst,
    const float4* __restrict__ z4, float4* __restrict__ out4, int n_nodes)
{
    int node = blockIdx.x * 4 + (threadIdx.x >> 6);
    if (node >= n_nodes) return;
    const int lane = threadIdx.x & 63;
    const int q    = lane >> 4;
    const int l16  = lane & 15;
    int beg = off[node], end = off[node + 1];
    int deg = end - beg;
    float adst = a_dst[node];

    float den = 0.f;
    float4 acc = make_float4(0.f, 0.f, 0.f, 0.f);

    if (deg <= 64) {
        int j = beg + lane;
        float e = -INFINITY; int sl = 0;
        if (j < end) {
            sl = bucket[j];
            e = a_src[sl] + adst;
            e = (e >= 0.f) ? e : NEG_SLOPE * e;
        }
        float m = e;
        #pragma unroll
        for (int o = 32; o > 0; o >>= 1) m = fmaxf(m, __shfl_xor(m, o, 64));
        float ex = (j < end) ? __expf(e - m) : 0.f;
        float exs = ex;
        #pragma unroll
        for (int o = 32; o > 0; o >>= 1) exs += __shfl_xor(exs, o, 64);
        den = exs;

        int ng = (deg + 3) >> 2;
        for (int g = 0; g < ng; ++g) {
            float w = __shfl(ex, g * 4 + q, 64);
            int   s = __shfl(sl, g * 4 + q, 64);
            float4 zr = z4[(size_t)s * 16 + l16];
            acc.x = fmaf(w, zr.x, acc.x);
            acc.y = fmaf(w, zr.y, acc.y);
            acc.z = fmaf(w, zr.z, acc.z);
            acc.w = fmaf(w, zr.w, acc.w);
        }
    } else {
        float m = -INFINITY;
        for (int c = beg; c < end; c += 64) {
            int j = c + lane;
            if (j < end) {
                float e = a_src[bucket[j]] + adst;
                e = (e >= 0.f) ? e : NEG_SLOPE * e;
                m = fmaxf(m, e);
            }
        }
        #pragma unroll
        for (int o = 32; o > 0; o >>= 1) m = fmaxf(m, __shfl_xor(m, o, 64));

        for (int c = beg; c < end; c += 64) {
            int j = c + lane;
            float ex = 0.f; int sl = 0;
            if (j < end) {
                sl = bucket[j];
                float e = a_src[sl] + adst;
                e = (e >= 0.f) ? e : NEG_SLOPE * e;
                ex = __expf(e - m);
            }
            float exs = ex;
            #pragma unroll
            for (int o = 32; o > 0; o >>= 1) exs += __shfl_xor(exs, o, 64);
            den += exs;

            int lim = end - c; if (lim > 64) lim = 64;
            int ng = (lim + 3) >> 2;
            for (int g = 0; g < ng; ++g) {
                float w = __shfl(ex, g * 4 + q, 64);
                int   s = __shfl(sl, g * 4 + q, 64);
                float4 zr = z4[(size_t)s * 16 + l16];
                acc.x = fmaf(w, zr.x, acc.x);
                acc.y = fmaf(w, zr.y, acc.y);
                acc.z = fmaf(w, zr.z, acc.z);
                acc.w = fmaf(w, zr.w, acc.w);
            }
        }
    }

    #pragma unroll
    for (int o = 16; o <= 32; o <<= 1) {
        acc.x += __shfl_xor(acc.x, o, 64);
        acc.y += __shfl_xor(acc.y, o, 64);
        acc.z += __shfl_xor(acc.z, o, 64);
        acc.w += __shfl_xor(acc.w, o, 64);
    }

    if (lane < 16) {
        float inv = (deg > 0) ? 1.f / den : 0.f;
        float4 o4 = make_float4(acc.x * inv, acc.y * inv, acc.z * inv, acc.w * inv);
        out4[(size_t)node * 16 + l16] = o4;
    }
}

extern "C" void kernel_launch(void* const* d_in, const int* in_sizes, int n_in,
                              void* d_out, int out_size, void* d_ws, size_t ws_size,
                              hipStream_t stream) {
    const float* h      = (const float*)d_in[0];
    const int*   src    = (const int*)d_in[1];
    const int*   dst    = (const int*)d_in[2];
    const float* fc_w   = (const float*)d_in[3];
    const float* attn_w = (const float*)d_in[4];

    const int n_nodes = in_sizes[0] / IN;
    const int n_edges = in_sizes[1];
    float* out = (float*)d_out;

    const int nb = (n_nodes + 1023) / 1024;

    // workspace layout
    char* p = (char*)d_ws;
    float*  z      = (float*)p;  p += (size_t)n_nodes * D * sizeof(float);
    float*  a_src  = (float*)p;  p += (size_t)n_nodes * sizeof(float);
    float*  a_dst  = (float*)p;  p += (size_t)n_nodes * sizeof(float);
    int*    deg    = (int*)p;    p += (size_t)n_nodes * sizeof(int);
    int*    off    = (int*)p;    p += ((size_t)n_nodes + 1) * sizeof(int);
    int*    cursor = (int*)p;    p += (size_t)n_nodes * sizeof(int);
    int*    bsum   = (int*)p;    p += 256 * sizeof(int);
    int*    bucket = (int*)p;    p += (size_t)n_edges * sizeof(int);

    hipMemsetAsync(deg, 0, (size_t)n_nodes * sizeof(int), stream);

    k_project<<<dim3((n_nodes + 63) / 64), dim3(256), 0, stream>>>(
        h, fc_w, attn_w, z, a_src, a_dst, n_nodes);
    k_hist<<<dim3((n_edges + 255) / 256), dim3(256), 0, stream>>>(
        dst, deg, n_edges);
    k_bsum<<<dim3(nb), dim3(1024), 0, stream>>>(deg, bsum, n_nodes);
    k_scanb<<<dim3(1), dim3(256), 0, stream>>>(bsum, nb);
    k_scanw<<<dim3(nb), dim3(1024), 0, stream>>>(deg, bsum, off, cursor, n_nodes);

    const int nodes_per_slice = (n_nodes + 7) / 8;
    const int epb = 1024;
    const int nch = (n_edges + epb - 1) / epb;
    k_fill<<<dim3(8 * nch), dim3(256), 0, stream>>>(
        src, dst, cursor, bucket, n_edges, nodes_per_slice, n_nodes, epb);

    k_node<<<dim3((n_nodes + 3) / 4), dim3(256), 0, stream>>>(
        off, bucket, a_src, a_dst, (const float4*)z, (float4*)out, n_nodes);
}